// Round 13
// baseline (167.649 us; speedup 1.0000x reference)
//
#include <hip/hip_runtime.h>

#define EPSF 1e-6f

typedef short bf16x8_t __attribute__((ext_vector_type(8)));
typedef float f32x4_t __attribute__((ext_vector_type(4)));

__device__ __forceinline__ ushort f2bf(float f) {
  union { float f; uint32_t u; } c; c.f = f;
  return (ushort)((c.u + 0x7FFFu + ((c.u >> 16) & 1u)) >> 16);
}
__device__ __forceinline__ float bf2f(ushort u) {
  union { uint32_t u; float f; } c; c.u = ((uint32_t)u) << 16;
  return c.f;
}

// swizzled byte offset, 64x64 bf16 tile (128-B rows): 16B-slot ^= row&7
// (attention kernels only)
#define SWB(row, kbyte) (((row) << 7) + ((kbyte) ^ (((row) & 7) << 4)))

// ============ f32 -> bf16 conversion for x, Wq, Wk, Wv, Wo ==================
__global__ __launch_bounds__(256) void cvt5_kernel(
    const float4* __restrict__ x, const float4* __restrict__ wq,
    const float4* __restrict__ wk, const float4* __restrict__ wv,
    const float4* __restrict__ wo,
    ushort4* __restrict__ xb, ushort4* __restrict__ wqb,
    ushort4* __restrict__ wkb, ushort4* __restrict__ wvb,
    ushort4* __restrict__ wob)
{
  const int i = blockIdx.x * 256 + threadIdx.x;   // float4 index, 0..2M-1
  const float4* src; ushort4* dst; int off;
  if (i < (1 << 20)) { src = x; dst = xb; off = i; }
  else {
    const int j = i - (1 << 20);
    const int r = j >> 18;
    off = j & ((1 << 18) - 1);
    src = (r == 0) ? wq : (r == 1) ? wk : (r == 2) ? wv : wo;
    dst = (r == 0) ? wqb : (r == 1) ? wkb : (r == 2) ? wvb : wob;
  }
  const float4 v = src[off];
  ushort4 o;
  o.x = f2bf(v.x); o.y = f2bf(v.y); o.z = f2bf(v.z); o.w = f2bf(v.w);
  dst[off] = o;
}

// ============ bf16 MFMA NT GEMM: C[m][n] = sum_k A[m][k]*B[n][k] ============
// r3/r11-verified structure (local optimum after r4/r5/r10/r12 A/Bs):
// 128 x BN tile, BK=32, SINGLE-buffer 2-barrier loop, linear LDS,
// global_load_lds width-16, no swizzle, no setprio.
// BN=64 everywhere (out_gemm at BN=64 measured ~660 TF > BN=128's ~600):
// more blocks/CU -> more wave-level overlap (m114 mechanism).
template<int BN, int OUT_BF16>
__device__ __forceinline__ void gemm_bt_mfma(
    const ushort* __restrict__ A, const ushort* __restrict__ B,
    void* __restrict__ C, const int K,
    const int N, const int row0, const int col0, const bool relu)
{
  constexpr int NFR = BN / 32;                 // B-frags per wave
  __shared__ __align__(16) uint As[2048];      // 128 x 32 bf16 = 8 KiB
  __shared__ __align__(16) uint Bs[BN * 16];   // BN x 32 bf16
  const int tid = threadIdx.x;
  const int lane = tid & 63;
  const int wv = tid >> 6;
  const int wr = (wv >> 1) * 64;
  const int wc = (wv & 1) * (BN / 2);

  f32x4_t acc[4][NFR];
#pragma unroll
  for (int m = 0; m < 4; ++m)
#pragma unroll
    for (int n = 0; n < NFR; ++n) acc[m][n] = (f32x4_t){0.f, 0.f, 0.f, 0.f};

  const int fr = lane & 15;
  const int kh = (lane >> 4) * 8;   // k element offset for fragment reads

  for (int k0 = 0; k0 < K; k0 += 32) {
    __syncthreads();   // prior iteration's ds_reads done before overwrite
#pragma unroll
    for (int is = 0; is < 2; ++is) {
      const int c = tid + (is << 8);
      const int row = c >> 2, kq = (c & 3) << 3;
      __builtin_amdgcn_global_load_lds(
          (const __attribute__((address_space(1))) void*)(A + (size_t)(row0 + row) * K + k0 + kq),
          (__attribute__((address_space(3))) void*)(As + (c & ~63) * 4), 16, 0, 0);
    }
#pragma unroll
    for (int is = 0; is < BN / 64; ++is) {
      const int c = tid + (is << 8);
      const int row = c >> 2, kq = (c & 3) << 3;
      __builtin_amdgcn_global_load_lds(
          (const __attribute__((address_space(1))) void*)(B + (size_t)(col0 + row) * K + k0 + kq),
          (__attribute__((address_space(3))) void*)(Bs + (c & ~63) * 4), 16, 0, 0);
    }
    __syncthreads();   // drains vmcnt -> LDS tiles ready

    bf16x8_t af[4], bfr[NFR];
#pragma unroll
    for (int m = 0; m < 4; ++m)
      af[m] = *(const bf16x8_t*)((const ushort*)As + (size_t)(wr + m * 16 + fr) * 32 + kh);
#pragma unroll
    for (int n = 0; n < NFR; ++n)
      bfr[n] = *(const bf16x8_t*)((const ushort*)Bs + (size_t)(wc + n * 16 + fr) * 32 + kh);
#pragma unroll
    for (int m = 0; m < 4; ++m)
#pragma unroll
      for (int n = 0; n < NFR; ++n)
        acc[m][n] = __builtin_amdgcn_mfma_f32_16x16x32_bf16(
            af[m], bfr[n], acc[m][n], 0, 0, 0);
  }

  const int rq = (lane >> 4) * 4;
#pragma unroll
  for (int m = 0; m < 4; ++m) {
#pragma unroll
    for (int r = 0; r < 4; ++r) {
      const size_t grow = (size_t)(row0 + wr + m * 16 + rq + r);
#pragma unroll
      for (int n = 0; n < NFR; ++n) {
        float val = acc[m][n][r];
        if (relu) val = fmaxf(val, 0.f) + EPSF;
        const size_t gcol = (size_t)(col0 + wc + n * 16 + fr);
        if (OUT_BF16) ((ushort*)C)[grow * N + gcol] = f2bf(val);
        else          ((float*)C)[grow * N + gcol] = val;
      }
    }
  }
}

// BN=64: grid (32, 48): which = y>>4, bcol = y&15 -> 1536 blocks = 6/CU
__global__ __launch_bounds__(256) void qkv_gemm_kernel(
    const ushort* __restrict__ xb,
    const ushort* __restrict__ wqb, const ushort* __restrict__ wkb,
    const ushort* __restrict__ wvb,
    ushort* __restrict__ q, ushort* __restrict__ k, ushort* __restrict__ v)
{
  const int which = blockIdx.y >> 4;
  const int bcol = blockIdx.y & 15;
  const ushort* B = (which == 0) ? wqb : (which == 1) ? wkb : wvb;
  ushort* C = (which == 0) ? q : (which == 1) ? k : v;
  gemm_bt_mfma<64, 1>(xb, B, C, 1024, 1024,
                      blockIdx.x * 128, bcol * 64, which < 2);
}

// 128x64 tiles -> 512 blocks = 2/CU
__global__ __launch_bounds__(256) void out_gemm_kernel(
    const ushort* __restrict__ at, const ushort* __restrict__ wob,
    float* __restrict__ out)
{
  gemm_bt_mfma<64, 0>(at, wob, out, 1024, 1024,
                      blockIdx.x * 128, blockIdx.y * 64, false);
}

// ================= chunked linear attention (bf16 MFMA) =====================
// q/k/v: (b*s, 1024) bf16 row-major, head h at cols h*64..h*64+63.
// seq = b*16+h (32 sequences), 32 chunks of 64 positions.
// kvs: [seq][chunk][m][d] bf16 per-chunk KV^T; kvsb: bf16 EXCLUSIVE prefix;
// ksum: [seq][chunk][d] fp32 (exclusive after scan).

__global__ __launch_bounds__(256) void chunk_sums_kernel(
    const ushort* __restrict__ kbuf, const ushort* __restrict__ vbuf,
    ushort* __restrict__ kvs, float* __restrict__ ksum)
{
  __shared__ __align__(16) uint Kt[2048];   // 64x64 bf16 swizzled
  __shared__ __align__(16) uint Vt[2048];
  const int chunk = blockIdx.x;
  const int seq = blockIdx.y;
  const int b = seq >> 4, h = seq & 15;
  const int tid = threadIdx.x;
  const size_t base = ((size_t)b * 2048 + chunk * 64) * 1024 + h * 64;

#pragma unroll
  for (int r = 0; r < 2; ++r) {
    const int idx = tid + (r << 8);       // 0..511
    const int j = idx >> 3;               // 0..63
    const int e0 = (idx & 7) << 3;        // 0,8,..,56
    const bf16x8_t kv8 = *(const bf16x8_t*)(kbuf + base + (size_t)j * 1024 + e0);
    const bf16x8_t vv8 = *(const bf16x8_t*)(vbuf + base + (size_t)j * 1024 + e0);
#pragma unroll
    for (int t = 0; t < 8; ++t) {
      *(ushort*)((char*)Kt + SWB(e0 + t, j * 2)) = (ushort)kv8[t];
      *(ushort*)((char*)Vt + SWB(e0 + t, j * 2)) = (ushort)vv8[t];
    }
  }
  __syncthreads();

  if (tid < 64) {
    float s = 0.f;
#pragma unroll
    for (int g = 0; g < 8; ++g) {
      const bf16x8_t kr = *(const bf16x8_t*)((char*)Kt + SWB(tid, g * 16));
#pragma unroll
      for (int t = 0; t < 8; ++t) s += bf2f((ushort)kr[t]);
    }
    ksum[((size_t)seq * 32 + chunk) * 64 + tid] = s;
  }

  const int lane = tid & 63;
  const int wv = tid >> 6;
  const int wm = (wv >> 1) * 32;
  const int wd = (wv & 1) * 32;
  const int fr = lane & 15;
  const int khb = (lane >> 4) * 16;

  f32x4_t acc[2][2];
#pragma unroll
  for (int m = 0; m < 2; ++m)
#pragma unroll
    for (int n = 0; n < 2; ++n) acc[m][n] = (f32x4_t){0.f, 0.f, 0.f, 0.f};

#pragma unroll
  for (int kk = 0; kk < 2; ++kk) {
    bf16x8_t av[2], bk[2];
#pragma unroll
    for (int m = 0; m < 2; ++m)
      av[m] = *(const bf16x8_t*)((char*)Vt + SWB(wm + m * 16 + fr, kk * 64 + khb));
#pragma unroll
    for (int n = 0; n < 2; ++n)
      bk[n] = *(const bf16x8_t*)((char*)Kt + SWB(wd + n * 16 + fr, kk * 64 + khb));
#pragma unroll
    for (int m = 0; m < 2; ++m)
#pragma unroll
      for (int n = 0; n < 2; ++n)
        acc[m][n] = __builtin_amdgcn_mfma_f32_16x16x32_bf16(
            av[m], bk[n], acc[m][n], 0, 0, 0);
  }

  const size_t kvbase = ((size_t)seq * 32 + chunk) << 12;
  const int rq = (lane >> 4) * 4;
#pragma unroll
  for (int m = 0; m < 2; ++m)
#pragma unroll
    for (int r = 0; r < 4; ++r) {
      const int mrow = wm + m * 16 + rq + r;
#pragma unroll
      for (int n = 0; n < 2; ++n) {
        const int dcol = wd + n * 16 + fr;
        kvs[kvbase + (size_t)mrow * 64 + dcol] = f2bf(acc[m][n][r]);
      }
    }
}

// exclusive prefix scan over chunks; bf16 in, fp32 accumulate, bf16 out.
// grid = 32 seq * 16 slices.
__global__ __launch_bounds__(256) void scan_kernel(
    const ushort* __restrict__ kvs, ushort* __restrict__ kvsb,
    float* __restrict__ ksum)
{
  const int slice = blockIdx.x & 15;
  const int seq = blockIdx.x >> 4;
  const int e = slice * 256 + threadIdx.x;   // 0..4095
  const size_t base = ((size_t)seq << 17) + e;
  ushort vals[32];
#pragma unroll
  for (int c = 0; c < 32; ++c) vals[c] = kvs[base + ((size_t)c << 12)];
  float run = 0.f;
#pragma unroll
  for (int c = 0; c < 32; ++c) {
    kvsb[base + ((size_t)c << 12)] = f2bf(run);
    run += bf2f(vals[c]);
  }
  if (slice == 0 && threadIdx.x < 64) {
    const size_t kb = (size_t)seq * 2048 + threadIdx.x;
    float kv2[32];
#pragma unroll
    for (int c = 0; c < 32; ++c) kv2[c] = ksum[kb + (size_t)c * 64];
    float run2 = 0.f;
#pragma unroll
    for (int c = 0; c < 32; ++c) {
      const float t = kv2[c];
      ksum[kb + (size_t)c * 64] = run2;
      run2 += t;
    }
  }
}

// Per (seq, chunk): S = QK^T (causal-masked) -> P bf16; O = P*V + Q*KVp;
// z_i = q_i . kcum_excl + sum_{j<=i} S_ij; out = O / z, written bf16.
__global__ __launch_bounds__(256) void attn_chunk_kernel(
    const ushort* __restrict__ qbuf, const ushort* __restrict__ kbuf,
    const ushort* __restrict__ vbuf, const ushort* __restrict__ kvsb,
    const float* __restrict__ ksum, ushort* __restrict__ attn)
{
  __shared__ __align__(16) uint Qs[2048];
  __shared__ __align__(16) uint Ks[2048];   // reused as KVp bf16
  __shared__ __align__(16) uint Vt[2048];
  __shared__ __align__(16) uint Pl[2048];
  __shared__ float ksp[64];
  __shared__ float zinv[64];
  const int chunk = blockIdx.x;
  const int seq = blockIdx.y;
  const int b = seq >> 4, h = seq & 15;
  const int tid = threadIdx.x;
  const size_t base = ((size_t)b * 2048 + chunk * 64) * 1024 + h * 64;

  // ---- stage Q, K straight (swizzled); V transposed ----
#pragma unroll
  for (int r = 0; r < 2; ++r) {
    const int idx = tid + (r << 8);
    const int row = idx >> 3;             // 0..63
    const int e0 = (idx & 7) << 3;        // element offset 0..56
    const int kb = e0 << 1;               // byte offset
    *(bf16x8_t*)((char*)Qs + SWB(row, kb)) =
        *(const bf16x8_t*)(qbuf + base + (size_t)row * 1024 + e0);
    *(bf16x8_t*)((char*)Ks + SWB(row, kb)) =
        *(const bf16x8_t*)(kbuf + base + (size_t)row * 1024 + e0);
    const bf16x8_t vv8 = *(const bf16x8_t*)(vbuf + base + (size_t)row * 1024 + e0);
#pragma unroll
    for (int t = 0; t < 8; ++t)
      *(ushort*)((char*)Vt + SWB(e0 + t, row * 2)) = (ushort)vv8[t];
  }
  if (tid < 64) ksp[tid] = ksum[((size_t)seq * 32 + chunk) * 64 + tid];
  __syncthreads();

  const int lane = tid & 63;
  const int wv = tid >> 6;
  const int wr = (wv >> 1) * 32;   // output row quadrant
  const int wc = (wv & 1) * 32;    // output col quadrant
  const int fr = lane & 15;
  const int khb = (lane >> 4) * 16;
  const int rq = (lane >> 4) * 4;

  // ---- S = Q K^T ----
  f32x4_t sf[2][2];
#pragma unroll
  for (int m = 0; m < 2; ++m)
#pragma unroll
    for (int n = 0; n < 2; ++n) sf[m][n] = (f32x4_t){0.f, 0.f, 0.f, 0.f};
#pragma unroll
  for (int kk = 0; kk < 2; ++kk) {
    bf16x8_t aq[2], bk[2];
#pragma unroll
    for (int m = 0; m < 2; ++m)
      aq[m] = *(const bf16x8_t*)((char*)Qs + SWB(wr + m * 16 + fr, kk * 64 + khb));
#pragma unroll
    for (int n = 0; n < 2; ++n)
      bk[n] = *(const bf16x8_t*)((char*)Ks + SWB(wc + n * 16 + fr, kk * 64 + khb));
#pragma unroll
    for (int m = 0; m < 2; ++m)
#pragma unroll
      for (int n = 0; n < 2; ++n)
        sf[m][n] = __builtin_amdgcn_mfma_f32_16x16x32_bf16(
            aq[m], bk[n], sf[m][n], 0, 0, 0);
  }
  __syncthreads();   // all S-frag LDS reads done; Ks reusable

  // ---- mask + write P (bf16); stage KVp (bf16 global -> swizzled LDS) ----
#pragma unroll
  for (int m = 0; m < 2; ++m)
#pragma unroll
    for (int r = 0; r < 4; ++r) {
      const int i = wr + m * 16 + rq + r;
#pragma unroll
      for (int n = 0; n < 2; ++n) {
        const int j = wc + n * 16 + fr;
        const float pv = (j <= i) ? sf[m][n][r] : 0.f;
        *(ushort*)((char*)Pl + SWB(i, j * 2)) = f2bf(pv);
      }
    }
  const size_t kvbase = ((size_t)seq * 32 + chunk) << 12;
#pragma unroll
  for (int r = 0; r < 2; ++r) {
    const int idx = tid + (r << 8);
    const int mrow = idx >> 3;
    const int d0 = (idx & 7) << 3;
    const bf16x8_t kv8 = *(const bf16x8_t*)(kvsb + kvbase + (size_t)mrow * 64 + d0);
    *(bf16x8_t*)((char*)Ks + SWB(mrow, d0 << 1)) = kv8;
  }
  __syncthreads();

  // ---- z on first 64 threads ----
  if (tid < 64) {
    const int i = tid;
    float dsum = 0.f, ssum = 0.f;
#pragma unroll
    for (int g = 0; g < 8; ++g) {
      const bf16x8_t qr = *(const bf16x8_t*)((char*)Qs + SWB(i, g * 16));
      const bf16x8_t pr = *(const bf16x8_t*)((char*)Pl + SWB(i, g * 16));
#pragma unroll
      for (int t = 0; t < 8; ++t) {
        dsum = fmaf(bf2f((ushort)qr[t]), ksp[g * 8 + t], dsum);
        ssum += bf2f((ushort)pr[t]);
      }
    }
    zinv[i] = 1.f / (dsum + ssum + EPSF);
  }

  // ---- O = P*V + Q*KVp ----
  f32x4_t of[2][2];
#pragma unroll
  for (int m = 0; m < 2; ++m)
#pragma unroll
    for (int n = 0; n < 2; ++n) of[m][n] = (f32x4_t){0.f, 0.f, 0.f, 0.f};
#pragma unroll
  for (int kk = 0; kk < 2; ++kk) {
    bf16x8_t ap[2], bv[2];
#pragma unroll
    for (int m = 0; m < 2; ++m)
      ap[m] = *(const bf16x8_t*)((char*)Pl + SWB(wr + m * 16 + fr, kk * 64 + khb));
#pragma unroll
    for (int n = 0; n < 2; ++n)
      bv[n] = *(const bf16x8_t*)((char*)Vt + SWB(wc + n * 16 + fr, kk * 64 + khb));
#pragma unroll
    for (int m = 0; m < 2; ++m)
#pragma unroll
      for (int n = 0; n < 2; ++n)
        of[m][n] = __builtin_amdgcn_mfma_f32_16x16x32_bf16(
            ap[m], bv[n], of[m][n], 0, 0, 0);
  }
#pragma unroll
  for (int kk = 0; kk < 2; ++kk) {
    bf16x8_t aq[2], bkv[2];
#pragma unroll
    for (int m = 0; m < 2; ++m)
      aq[m] = *(const bf16x8_t*)((char*)Qs + SWB(wr + m * 16 + fr, kk * 64 + khb));
#pragma unroll
    for (int n = 0; n < 2; ++n)
      bkv[n] = *(const bf16x8_t*)((char*)Ks + SWB(wc + n * 16 + fr, kk * 64 + khb));
#pragma unroll
    for (int m = 0; m < 2; ++m)
#pragma unroll
      for (int n = 0; n < 2; ++n)
        of[m][n] = __builtin_amdgcn_mfma_f32_16x16x32_bf16(
            aq[m], bkv[n], of[m][n], 0, 0, 0);
  }
  __syncthreads();   // zinv ready

  // ---- scale + write bf16 ----
#pragma unroll
  for (int m = 0; m < 2; ++m)
#pragma unroll
    for (int r = 0; r < 4; ++r) {
      const int i = wr + m * 16 + rq + r;
      const float z = zinv[i];
#pragma unroll
      for (int n = 0; n < 2; ++n) {
        const int mcol = wc + n * 16 + fr;
        attn[base + (size_t)i * 1024 + mcol] = f2bf(of[m][n][r] * z);
      }
    }
}

// ================= launch ==================================================
extern "C" void kernel_launch(void* const* d_in, const int* in_sizes, int n_in,
                              void* d_out, int out_size, void* d_ws, size_t ws_size,
                              hipStream_t stream)
{
  (void)in_sizes; (void)n_in; (void)out_size; (void)ws_size;
  const float* x  = (const float*)d_in[0];
  const float* Wq = (const float*)d_in[1];
  const float* Wk = (const float*)d_in[2];
  const float* Wv = (const float*)d_in[3];
  const float* Wo = (const float*)d_in[4];
  float* out = (float*)d_out;

  const size_t NM = (size_t)4096 * 1024;
  ushort* xb  = (ushort*)d_ws;          // bf16 x, NM
  ushort* wqb = xb + NM;                // bf16 weights, 1M each
  ushort* wkb = wqb + (1 << 20);
  ushort* wvb = wkb + (1 << 20);
  ushort* wob = wvb + (1 << 20);
  ushort* qb  = wob + (1 << 20);        // bf16 q/k/v, NM each
  ushort* kb  = qb + NM;
  ushort* vb  = kb + NM;
  ushort* at  = vb + NM;                // bf16 attn out, NM
  float*  ksm = (float*)(at + NM);      // fp32, 65536
  ushort* kvs = (ushort*)(ksm + 65536); // bf16 per-chunk kvsum, NM
  ushort* kvsb = kvs + NM;              // bf16 exclusive prefix, NM

  cvt5_kernel<<<8192, 256, 0, stream>>>(
      (const float4*)x, (const float4*)Wq, (const float4*)Wk,
      (const float4*)Wv, (const float4*)Wo,
      (ushort4*)xb, (ushort4*)wqb, (ushort4*)wkb, (ushort4*)wvb, (ushort4*)wob);
  qkv_gemm_kernel<<<dim3(32, 48), 256, 0, stream>>>(xb, wqb, wkb, wvb, qb, kb, vb);
  chunk_sums_kernel<<<dim3(32, 32), 256, 0, stream>>>(kb, vb, kvs, ksm);
  scan_kernel<<<512, 256, 0, stream>>>(kvs, kvsb, ksm);
  attn_chunk_kernel<<<dim3(32, 32), 256, 0, stream>>>(qb, kb, vb, kvsb, ksm, at);
  out_gemm_kernel<<<dim3(32, 16), 256, 0, stream>>>(at, wob, out);
}

// Round 14
// 156.761 us; speedup vs baseline: 1.0695x; 1.0695x over previous
//
#include <hip/hip_runtime.h>

#define EPSF 1e-6f

typedef short bf16x8_t __attribute__((ext_vector_type(8)));
typedef float f32x4_t __attribute__((ext_vector_type(4)));

__device__ __forceinline__ ushort f2bf(float f) {
  union { float f; uint32_t u; } c; c.f = f;
  return (ushort)((c.u + 0x7FFFu + ((c.u >> 16) & 1u)) >> 16);
}
__device__ __forceinline__ float bf2f(ushort u) {
  union { uint32_t u; float f; } c; c.u = ((uint32_t)u) << 16;
  return c.f;
}

// swizzled byte offset, 64x64 bf16 tile (128-B rows): 16B-slot ^= row&7
// (attention kernels only)
#define SWB(row, kbyte) (((row) << 7) + ((kbyte) ^ (((row) & 7) << 4)))

// ============ f32 -> bf16 conversion for x, Wq, Wk, Wv, Wo ==================
__global__ __launch_bounds__(256) void cvt5_kernel(
    const float4* __restrict__ x, const float4* __restrict__ wq,
    const float4* __restrict__ wk, const float4* __restrict__ wv,
    const float4* __restrict__ wo,
    ushort4* __restrict__ xb, ushort4* __restrict__ wqb,
    ushort4* __restrict__ wkb, ushort4* __restrict__ wvb,
    ushort4* __restrict__ wob)
{
  const int i = blockIdx.x * 256 + threadIdx.x;   // float4 index, 0..2M-1
  const float4* src; ushort4* dst; int off;
  if (i < (1 << 20)) { src = x; dst = xb; off = i; }
  else {
    const int j = i - (1 << 20);
    const int r = j >> 18;
    off = j & ((1 << 18) - 1);
    src = (r == 0) ? wq : (r == 1) ? wk : (r == 2) ? wv : wo;
    dst = (r == 0) ? wqb : (r == 1) ? wkb : (r == 2) ? wvb : wob;
  }
  const float4 v = src[off];
  ushort4 o;
  o.x = f2bf(v.x); o.y = f2bf(v.y); o.z = f2bf(v.z); o.w = f2bf(v.w);
  dst[off] = o;
}

// ============ bf16 MFMA NT GEMM: C[m][n] = sum_k A[m][k]*B[n][k] ============
// r11-verified optimum (after r4/r5/r10/r12/r13 A/Bs closed schedule+tile
// space): 128 x BN tile, BK=32, SINGLE-buffer 2-barrier loop, linear LDS,
// global_load_lds width-16, no swizzle, no setprio. ONE instantiation per
// kernel (runtime relu) -> no duplicated __shared__.
// qkv: BN=128 (16 MFMA/K-step/wave beats higher occupancy).
// out: BN=64 (512 blocks = 2/CU beats 256 = 1/CU at this shape).
template<int BN, int OUT_BF16>
__device__ __forceinline__ void gemm_bt_mfma(
    const ushort* __restrict__ A, const ushort* __restrict__ B,
    void* __restrict__ C, const int K,
    const int N, const int row0, const int col0, const bool relu)
{
  constexpr int NFR = BN / 32;                 // B-frags per wave
  __shared__ __align__(16) uint As[2048];      // 128 x 32 bf16 = 8 KiB
  __shared__ __align__(16) uint Bs[BN * 16];   // BN x 32 bf16
  const int tid = threadIdx.x;
  const int lane = tid & 63;
  const int wv = tid >> 6;
  const int wr = (wv >> 1) * 64;
  const int wc = (wv & 1) * (BN / 2);

  f32x4_t acc[4][NFR];
#pragma unroll
  for (int m = 0; m < 4; ++m)
#pragma unroll
    for (int n = 0; n < NFR; ++n) acc[m][n] = (f32x4_t){0.f, 0.f, 0.f, 0.f};

  const int fr = lane & 15;
  const int kh = (lane >> 4) * 8;   // k element offset for fragment reads

  for (int k0 = 0; k0 < K; k0 += 32) {
    __syncthreads();   // prior iteration's ds_reads done before overwrite
#pragma unroll
    for (int is = 0; is < 2; ++is) {
      const int c = tid + (is << 8);
      const int row = c >> 2, kq = (c & 3) << 3;
      __builtin_amdgcn_global_load_lds(
          (const __attribute__((address_space(1))) void*)(A + (size_t)(row0 + row) * K + k0 + kq),
          (__attribute__((address_space(3))) void*)(As + (c & ~63) * 4), 16, 0, 0);
    }
#pragma unroll
    for (int is = 0; is < BN / 64; ++is) {
      const int c = tid + (is << 8);
      const int row = c >> 2, kq = (c & 3) << 3;
      __builtin_amdgcn_global_load_lds(
          (const __attribute__((address_space(1))) void*)(B + (size_t)(col0 + row) * K + k0 + kq),
          (__attribute__((address_space(3))) void*)(Bs + (c & ~63) * 4), 16, 0, 0);
    }
    __syncthreads();   // drains vmcnt -> LDS tiles ready

    bf16x8_t af[4], bfr[NFR];
#pragma unroll
    for (int m = 0; m < 4; ++m)
      af[m] = *(const bf16x8_t*)((const ushort*)As + (size_t)(wr + m * 16 + fr) * 32 + kh);
#pragma unroll
    for (int n = 0; n < NFR; ++n)
      bfr[n] = *(const bf16x8_t*)((const ushort*)Bs + (size_t)(wc + n * 16 + fr) * 32 + kh);
#pragma unroll
    for (int m = 0; m < 4; ++m)
#pragma unroll
      for (int n = 0; n < NFR; ++n)
        acc[m][n] = __builtin_amdgcn_mfma_f32_16x16x32_bf16(
            af[m], bfr[n], acc[m][n], 0, 0, 0);
  }

  const int rq = (lane >> 4) * 4;
#pragma unroll
  for (int m = 0; m < 4; ++m) {
#pragma unroll
    for (int r = 0; r < 4; ++r) {
      const size_t grow = (size_t)(row0 + wr + m * 16 + rq + r);
#pragma unroll
      for (int n = 0; n < NFR; ++n) {
        float val = acc[m][n][r];
        if (relu) val = fmaxf(val, 0.f) + EPSF;
        const size_t gcol = (size_t)(col0 + wc + n * 16 + fr);
        if (OUT_BF16) ((ushort*)C)[grow * N + gcol] = f2bf(val);
        else          ((float*)C)[grow * N + gcol] = val;
      }
    }
  }
}

__global__ __launch_bounds__(256) void qkv_gemm_kernel(
    const ushort* __restrict__ xb,
    const ushort* __restrict__ wqb, const ushort* __restrict__ wkb,
    const ushort* __restrict__ wvb,
    ushort* __restrict__ q, ushort* __restrict__ k, ushort* __restrict__ v)
{
  const int which = blockIdx.y >> 3;
  const int bcol = blockIdx.y & 7;
  const ushort* B = (which == 0) ? wqb : (which == 1) ? wkb : wvb;
  ushort* C = (which == 0) ? q : (which == 1) ? k : v;
  gemm_bt_mfma<128, 1>(xb, B, C, 1024, 1024,
                       blockIdx.x * 128, bcol * 128, which < 2);
}

// 128x64 tiles -> 512 blocks = 2/CU
__global__ __launch_bounds__(256) void out_gemm_kernel(
    const ushort* __restrict__ at, const ushort* __restrict__ wob,
    float* __restrict__ out)
{
  gemm_bt_mfma<64, 0>(at, wob, out, 1024, 1024,
                      blockIdx.x * 128, blockIdx.y * 64, false);
}

// ================= chunked linear attention (bf16 MFMA) =====================
// q/k/v: (b*s, 1024) bf16 row-major, head h at cols h*64..h*64+63.
// seq = b*16+h (32 sequences), 32 chunks of 64 positions.
// kvs: [seq][chunk][m][d] bf16 per-chunk KV^T; kvsb: bf16 EXCLUSIVE prefix;
// ksum: [seq][chunk][d] fp32 (exclusive after scan).

__global__ __launch_bounds__(256) void chunk_sums_kernel(
    const ushort* __restrict__ kbuf, const ushort* __restrict__ vbuf,
    ushort* __restrict__ kvs, float* __restrict__ ksum)
{
  __shared__ __align__(16) uint Kt[2048];   // 64x64 bf16 swizzled
  __shared__ __align__(16) uint Vt[2048];
  const int chunk = blockIdx.x;
  const int seq = blockIdx.y;
  const int b = seq >> 4, h = seq & 15;
  const int tid = threadIdx.x;
  const size_t base = ((size_t)b * 2048 + chunk * 64) * 1024 + h * 64;

#pragma unroll
  for (int r = 0; r < 2; ++r) {
    const int idx = tid + (r << 8);       // 0..511
    const int j = idx >> 3;               // 0..63
    const int e0 = (idx & 7) << 3;        // 0,8,..,56
    const bf16x8_t kv8 = *(const bf16x8_t*)(kbuf + base + (size_t)j * 1024 + e0);
    const bf16x8_t vv8 = *(const bf16x8_t*)(vbuf + base + (size_t)j * 1024 + e0);
#pragma unroll
    for (int t = 0; t < 8; ++t) {
      *(ushort*)((char*)Kt + SWB(e0 + t, j * 2)) = (ushort)kv8[t];
      *(ushort*)((char*)Vt + SWB(e0 + t, j * 2)) = (ushort)vv8[t];
    }
  }
  __syncthreads();

  if (tid < 64) {
    float s = 0.f;
#pragma unroll
    for (int g = 0; g < 8; ++g) {
      const bf16x8_t kr = *(const bf16x8_t*)((char*)Kt + SWB(tid, g * 16));
#pragma unroll
      for (int t = 0; t < 8; ++t) s += bf2f((ushort)kr[t]);
    }
    ksum[((size_t)seq * 32 + chunk) * 64 + tid] = s;
  }

  const int lane = tid & 63;
  const int wv = tid >> 6;
  const int wm = (wv >> 1) * 32;
  const int wd = (wv & 1) * 32;
  const int fr = lane & 15;
  const int khb = (lane >> 4) * 16;

  f32x4_t acc[2][2];
#pragma unroll
  for (int m = 0; m < 2; ++m)
#pragma unroll
    for (int n = 0; n < 2; ++n) acc[m][n] = (f32x4_t){0.f, 0.f, 0.f, 0.f};

#pragma unroll
  for (int kk = 0; kk < 2; ++kk) {
    bf16x8_t av[2], bk[2];
#pragma unroll
    for (int m = 0; m < 2; ++m)
      av[m] = *(const bf16x8_t*)((char*)Vt + SWB(wm + m * 16 + fr, kk * 64 + khb));
#pragma unroll
    for (int n = 0; n < 2; ++n)
      bk[n] = *(const bf16x8_t*)((char*)Kt + SWB(wd + n * 16 + fr, kk * 64 + khb));
#pragma unroll
    for (int m = 0; m < 2; ++m)
#pragma unroll
      for (int n = 0; n < 2; ++n)
        acc[m][n] = __builtin_amdgcn_mfma_f32_16x16x32_bf16(
            av[m], bk[n], acc[m][n], 0, 0, 0);
  }

  const size_t kvbase = ((size_t)seq * 32 + chunk) << 12;
  const int rq = (lane >> 4) * 4;
#pragma unroll
  for (int m = 0; m < 2; ++m)
#pragma unroll
    for (int r = 0; r < 4; ++r) {
      const int mrow = wm + m * 16 + rq + r;
#pragma unroll
      for (int n = 0; n < 2; ++n) {
        const int dcol = wd + n * 16 + fr;
        kvs[kvbase + (size_t)mrow * 64 + dcol] = f2bf(acc[m][n][r]);
      }
    }
}

// exclusive prefix scan over chunks; bf16 in, fp32 accumulate, bf16 out.
// grid = 32 seq * 16 slices.
__global__ __launch_bounds__(256) void scan_kernel(
    const ushort* __restrict__ kvs, ushort* __restrict__ kvsb,
    float* __restrict__ ksum)
{
  const int slice = blockIdx.x & 15;
  const int seq = blockIdx.x >> 4;
  const int e = slice * 256 + threadIdx.x;   // 0..4095
  const size_t base = ((size_t)seq << 17) + e;
  ushort vals[32];
#pragma unroll
  for (int c = 0; c < 32; ++c) vals[c] = kvs[base + ((size_t)c << 12)];
  float run = 0.f;
#pragma unroll
  for (int c = 0; c < 32; ++c) {
    kvsb[base + ((size_t)c << 12)] = f2bf(run);
    run += bf2f(vals[c]);
  }
  if (slice == 0 && threadIdx.x < 64) {
    const size_t kb = (size_t)seq * 2048 + threadIdx.x;
    float kv2[32];
#pragma unroll
    for (int c = 0; c < 32; ++c) kv2[c] = ksum[kb + (size_t)c * 64];
    float run2 = 0.f;
#pragma unroll
    for (int c = 0; c < 32; ++c) {
      const float t = kv2[c];
      ksum[kb + (size_t)c * 64] = run2;
      run2 += t;
    }
  }
}

// Per (seq, chunk): S = QK^T (causal-masked) -> P bf16; O = P*V + Q*KVp;
// z_i = q_i . kcum_excl + sum_{j<=i} S_ij; out = O / z, written bf16.
__global__ __launch_bounds__(256) void attn_chunk_kernel(
    const ushort* __restrict__ qbuf, const ushort* __restrict__ kbuf,
    const ushort* __restrict__ vbuf, const ushort* __restrict__ kvsb,
    const float* __restrict__ ksum, ushort* __restrict__ attn)
{
  __shared__ __align__(16) uint Qs[2048];
  __shared__ __align__(16) uint Ks[2048];   // reused as KVp bf16
  __shared__ __align__(16) uint Vt[2048];
  __shared__ __align__(16) uint Pl[2048];
  __shared__ float ksp[64];
  __shared__ float zinv[64];
  const int chunk = blockIdx.x;
  const int seq = blockIdx.y;
  const int b = seq >> 4, h = seq & 15;
  const int tid = threadIdx.x;
  const size_t base = ((size_t)b * 2048 + chunk * 64) * 1024 + h * 64;

  // ---- stage Q, K straight (swizzled); V transposed ----
#pragma unroll
  for (int r = 0; r < 2; ++r) {
    const int idx = tid + (r << 8);
    const int row = idx >> 3;             // 0..63
    const int e0 = (idx & 7) << 3;        // element offset 0..56
    const int kb = e0 << 1;               // byte offset
    *(bf16x8_t*)((char*)Qs + SWB(row, kb)) =
        *(const bf16x8_t*)(qbuf + base + (size_t)row * 1024 + e0);
    *(bf16x8_t*)((char*)Ks + SWB(row, kb)) =
        *(const bf16x8_t*)(kbuf + base + (size_t)row * 1024 + e0);
    const bf16x8_t vv8 = *(const bf16x8_t*)(vbuf + base + (size_t)row * 1024 + e0);
#pragma unroll
    for (int t = 0; t < 8; ++t)
      *(ushort*)((char*)Vt + SWB(e0 + t, row * 2)) = (ushort)vv8[t];
  }
  if (tid < 64) ksp[tid] = ksum[((size_t)seq * 32 + chunk) * 64 + tid];
  __syncthreads();

  const int lane = tid & 63;
  const int wv = tid >> 6;
  const int wr = (wv >> 1) * 32;   // output row quadrant
  const int wc = (wv & 1) * 32;    // output col quadrant
  const int fr = lane & 15;
  const int khb = (lane >> 4) * 16;
  const int rq = (lane >> 4) * 4;

  // ---- S = Q K^T ----
  f32x4_t sf[2][2];
#pragma unroll
  for (int m = 0; m < 2; ++m)
#pragma unroll
    for (int n = 0; n < 2; ++n) sf[m][n] = (f32x4_t){0.f, 0.f, 0.f, 0.f};
#pragma unroll
  for (int kk = 0; kk < 2; ++kk) {
    bf16x8_t aq[2], bk[2];
#pragma unroll
    for (int m = 0; m < 2; ++m)
      aq[m] = *(const bf16x8_t*)((char*)Qs + SWB(wr + m * 16 + fr, kk * 64 + khb));
#pragma unroll
    for (int n = 0; n < 2; ++n)
      bk[n] = *(const bf16x8_t*)((char*)Ks + SWB(wc + n * 16 + fr, kk * 64 + khb));
#pragma unroll
    for (int m = 0; m < 2; ++m)
#pragma unroll
      for (int n = 0; n < 2; ++n)
        sf[m][n] = __builtin_amdgcn_mfma_f32_16x16x32_bf16(
            aq[m], bk[n], sf[m][n], 0, 0, 0);
  }
  __syncthreads();   // all S-frag LDS reads done; Ks reusable

  // ---- mask + write P (bf16); stage KVp (bf16 global -> swizzled LDS) ----
#pragma unroll
  for (int m = 0; m < 2; ++m)
#pragma unroll
    for (int r = 0; r < 4; ++r) {
      const int i = wr + m * 16 + rq + r;
#pragma unroll
      for (int n = 0; n < 2; ++n) {
        const int j = wc + n * 16 + fr;
        const float pv = (j <= i) ? sf[m][n][r] : 0.f;
        *(ushort*)((char*)Pl + SWB(i, j * 2)) = f2bf(pv);
      }
    }
  const size_t kvbase = ((size_t)seq * 32 + chunk) << 12;
#pragma unroll
  for (int r = 0; r < 2; ++r) {
    const int idx = tid + (r << 8);
    const int mrow = idx >> 3;
    const int d0 = (idx & 7) << 3;
    const bf16x8_t kv8 = *(const bf16x8_t*)(kvsb + kvbase + (size_t)mrow * 64 + d0);
    *(bf16x8_t*)((char*)Ks + SWB(mrow, d0 << 1)) = kv8;
  }
  __syncthreads();

  // ---- z on first 64 threads ----
  if (tid < 64) {
    const int i = tid;
    float dsum = 0.f, ssum = 0.f;
#pragma unroll
    for (int g = 0; g < 8; ++g) {
      const bf16x8_t qr = *(const bf16x8_t*)((char*)Qs + SWB(i, g * 16));
      const bf16x8_t pr = *(const bf16x8_t*)((char*)Pl + SWB(i, g * 16));
#pragma unroll
      for (int t = 0; t < 8; ++t) {
        dsum = fmaf(bf2f((ushort)qr[t]), ksp[g * 8 + t], dsum);
        ssum += bf2f((ushort)pr[t]);
      }
    }
    zinv[i] = 1.f / (dsum + ssum + EPSF);
  }

  // ---- O = P*V + Q*KVp ----
  f32x4_t of[2][2];
#pragma unroll
  for (int m = 0; m < 2; ++m)
#pragma unroll
    for (int n = 0; n < 2; ++n) of[m][n] = (f32x4_t){0.f, 0.f, 0.f, 0.f};
#pragma unroll
  for (int kk = 0; kk < 2; ++kk) {
    bf16x8_t ap[2], bv[2];
#pragma unroll
    for (int m = 0; m < 2; ++m)
      ap[m] = *(const bf16x8_t*)((char*)Pl + SWB(wr + m * 16 + fr, kk * 64 + khb));
#pragma unroll
    for (int n = 0; n < 2; ++n)
      bv[n] = *(const bf16x8_t*)((char*)Vt + SWB(wc + n * 16 + fr, kk * 64 + khb));
#pragma unroll
    for (int m = 0; m < 2; ++m)
#pragma unroll
      for (int n = 0; n < 2; ++n)
        of[m][n] = __builtin_amdgcn_mfma_f32_16x16x32_bf16(
            ap[m], bv[n], of[m][n], 0, 0, 0);
  }
#pragma unroll
  for (int kk = 0; kk < 2; ++kk) {
    bf16x8_t aq[2], bkv[2];
#pragma unroll
    for (int m = 0; m < 2; ++m)
      aq[m] = *(const bf16x8_t*)((char*)Qs + SWB(wr + m * 16 + fr, kk * 64 + khb));
#pragma unroll
    for (int n = 0; n < 2; ++n)
      bkv[n] = *(const bf16x8_t*)((char*)Ks + SWB(wc + n * 16 + fr, kk * 64 + khb));
#pragma unroll
    for (int m = 0; m < 2; ++m)
#pragma unroll
      for (int n = 0; n < 2; ++n)
        of[m][n] = __builtin_amdgcn_mfma_f32_16x16x32_bf16(
            aq[m], bkv[n], of[m][n], 0, 0, 0);
  }
  __syncthreads();   // zinv ready

  // ---- scale + write bf16 ----
#pragma unroll
  for (int m = 0; m < 2; ++m)
#pragma unroll
    for (int r = 0; r < 4; ++r) {
      const int i = wr + m * 16 + rq + r;
      const float z = zinv[i];
#pragma unroll
      for (int n = 0; n < 2; ++n) {
        const int mcol = wc + n * 16 + fr;
        attn[base + (size_t)i * 1024 + mcol] = f2bf(of[m][n][r] * z);
      }
    }
}

// ================= launch ==================================================
extern "C" void kernel_launch(void* const* d_in, const int* in_sizes, int n_in,
                              void* d_out, int out_size, void* d_ws, size_t ws_size,
                              hipStream_t stream)
{
  (void)in_sizes; (void)n_in; (void)out_size; (void)ws_size;
  const float* x  = (const float*)d_in[0];
  const float* Wq = (const float*)d_in[1];
  const float* Wk = (const float*)d_in[2];
  const float* Wv = (const float*)d_in[3];
  const float* Wo = (const float*)d_in[4];
  float* out = (float*)d_out;

  const size_t NM = (size_t)4096 * 1024;
  ushort* xb  = (ushort*)d_ws;          // bf16 x, NM
  ushort* wqb = xb + NM;                // bf16 weights, 1M each
  ushort* wkb = wqb + (1 << 20);
  ushort* wvb = wkb + (1 << 20);
  ushort* wob = wvb + (1 << 20);
  ushort* qb  = wob + (1 << 20);        // bf16 q/k/v, NM each
  ushort* kb  = qb + NM;
  ushort* vb  = kb + NM;
  ushort* at  = vb + NM;                // bf16 attn out, NM
  float*  ksm = (float*)(at + NM);      // fp32, 65536
  ushort* kvs = (ushort*)(ksm + 65536); // bf16 per-chunk kvsum, NM
  ushort* kvsb = kvs + NM;              // bf16 exclusive prefix, NM

  cvt5_kernel<<<8192, 256, 0, stream>>>(
      (const float4*)x, (const float4*)Wq, (const float4*)Wk,
      (const float4*)Wv, (const float4*)Wo,
      (ushort4*)xb, (ushort4*)wqb, (ushort4*)wkb, (ushort4*)wvb, (ushort4*)wob);
  qkv_gemm_kernel<<<dim3(32, 24), 256, 0, stream>>>(xb, wqb, wkb, wvb, qb, kb, vb);
  chunk_sums_kernel<<<dim3(32, 32), 256, 0, stream>>>(kb, vb, kvs, ksm);
  scan_kernel<<<512, 256, 0, stream>>>(kvs, kvsb, ksm);
  attn_chunk_kernel<<<dim3(32, 32), 256, 0, stream>>>(qb, kb, vb, kvsb, ksm, at);
  out_gemm_kernel<<<dim3(32, 16), 256, 0, stream>>>(at, wob, out);
}